// Round 3
// baseline (252.645 us; speedup 1.0000x reference)
//
#include <hip/hip_runtime.h>
#include <hip/hip_cooperative_groups.h>
#include <math.h>

namespace cg = cooperative_groups;

#define NCLS 80
#define BB   32
#define NBOX 50
#define CC   85   // 5 + NUM_CLASSES

#define GRID1 1024   // 4 blocks/CU on 256 CUs -> co-resident for grid.sync
#define BLK1  256

__device__ __forceinline__ float clip10(float x) {
    return fminf(fmaxf(x, -10.f), 10.f);
}

// BCE with target 0: max(x,0) + log1p(exp(-|x|))
__device__ __forceinline__ float bce0(float x) {
    return fmaxf(x, 0.f) + __logf(1.f + __expf(-fabsf(x)));
}

// ---------------------------------------------------------------------------
// Shared device logic: dense base sums + sparse corrections -> part[9].
//   part[3s+0] = sum ch 0..3  clip(x)^2   (+ box corr: (pb-v)^2 - pb^2, last-write-wins)
//   part[3s+1] = sum ch 4     BCE(clip,0) (+ obj corr: -x per target cell, set-union)
//   part[3s+2] = sum ch 5..84 BCE(clip,0) (+ cls corr: -x per (cell,label), set-union)
// ---------------------------------------------------------------------------
__device__ __forceinline__ void compute_block_partials(
    const float* __restrict__ p0, const float* __restrict__ p1,
    const float* __restrict__ p2,
    const float* __restrict__ boxes, const int* __restrict__ labels,
    int bid, int nblocks, double* __restrict__ partial)
{
    const int tid = bid * BLK1 + threadIdx.x;
    const int nth = nblocks * BLK1;
    const float* ps[3] = {p0, p1, p2};
    const int hw4s[3]  = {64*64/4, 32*32/4, 16*16/4};

    float part[9];
    #pragma unroll
    for (int s = 0; s < 3; ++s) {
        const float4* p = (const float4*)ps[s];
        const int hw4 = hw4s[s];                 // pow2: div = shift
        const int n4  = BB * CC * hw4;
        float bx = 0.f, ob = 0.f, cl = 0.f;
        for (int i = tid; i < n4; i += nth) {
            float4 v = p[i];
            int c = (i / hw4) % CC;              // channel (wave-uniform)
            float a0 = clip10(v.x), a1 = clip10(v.y);
            float a2 = clip10(v.z), a3 = clip10(v.w);
            if (c < 4) {
                bx += a0*a0 + a1*a1 + a2*a2 + a3*a3;
            } else if (c == 4) {
                ob += bce0(a0) + bce0(a1) + bce0(a2) + bce0(a3);
            } else {
                cl += bce0(a0) + bce0(a1) + bce0(a2) + bce0(a3);
            }
        }
        part[3*s+0] = bx; part[3*s+1] = ob; part[3*s+2] = cl;
    }

    // ---- sparse corrections (blocks 0..95, wave 0) ----
    __shared__ int   s_cell[NBOX];
    __shared__ int   s_lab[NBOX];
    __shared__ float s_vx[NBOX], s_vy[NBOX], s_vw[NBOX], s_vh[NBOX];

    const bool doCorr = (bid < 3 * BB);
    const int  cs = bid / BB;                    // scale
    const int  cb = bid % BB;                    // image
    const int  Ws[3] = {64, 32, 16};

    if (doCorr && threadIdx.x < 64) {
        const int n = threadIdx.x;
        const int W = Ws[cs];
        if (n < NBOX) {
            const float* bp = boxes + ((size_t)cb * NBOX + n) * 4;
            float gx = bp[0] * (float)W;
            float gy = bp[1] * (float)W;
            int gi = min((int)gx, W - 1);   // gx > 0 always
            int gj = min((int)gy, W - 1);
            s_cell[n] = gj * W + gi;
            s_lab[n]  = labels[cb * NBOX + n];
            s_vx[n] = gx - (float)gi;
            s_vy[n] = gy - (float)gj;
            s_vw[n] = bp[2];
            s_vh[n] = bp[3];
        }
    }
    __syncthreads();
    if (doCorr && threadIdx.x < 64) {
        const int n = threadIdx.x;
        const int W = Ws[cs], hw = W * W;
        const float* pred = ps[cs];
        float cbx = 0.f, cob = 0.f, ccl = 0.f;
        if (n < NBOX) {
            const int cell = s_cell[n], lab = s_lab[n];
            bool lastCell = true, lastCls = true;
            for (int m = n + 1; m < NBOX; ++m) {
                if (s_cell[m] == cell) {
                    lastCell = false;
                    if (s_lab[m] == lab) lastCls = false;
                }
            }
            const float* pb_base = pred + (size_t)(cb * CC) * hw + cell;
            if (lastCell) {
                float vals[4] = {s_vx[n], s_vy[n], s_vw[n], s_vh[n]};
                #pragma unroll
                for (int c = 0; c < 4; ++c) {
                    float pb = clip10(pb_base[c * hw]);
                    float d  = pb - vals[c];
                    cbx += d * d - pb * pb;
                }
                float po = clip10(pb_base[4 * hw]);
                cob -= po;                       // BCE(x,1) - BCE(x,0) = -x
            }
            if (lastCls) {
                float pc = clip10(pb_base[(5 + lab) * hw]);
                ccl -= pc;
            }
        }
        #pragma unroll
        for (int off = 32; off > 0; off >>= 1) {
            cbx += __shfl_down(cbx, off);
            cob += __shfl_down(cob, off);
            ccl += __shfl_down(ccl, off);
        }
        if (n == 0) {
            part[3*cs+0] += cbx;
            part[3*cs+1] += cob;
            part[3*cs+2] += ccl;
        }
    }

    // ---- wave64 shuffle reduce each of the 9 sums ----
    #pragma unroll
    for (int k = 0; k < 9; ++k) {
        float v = part[k];
        #pragma unroll
        for (int off = 32; off > 0; off >>= 1) v += __shfl_down(v, off);
        part[k] = v;
    }
    __shared__ float sred[BLK1/64][9];
    const int wave = threadIdx.x >> 6;
    const int lane = threadIdx.x & 63;
    if (lane == 0) {
        #pragma unroll
        for (int k = 0; k < 9; ++k) sred[wave][k] = part[k];
    }
    __syncthreads();
    if (threadIdx.x == 0) {
        double* o = partial + (size_t)bid * 9;
        #pragma unroll
        for (int k = 0; k < 9; ++k)
            o[k] = (double)(sred[0][k] + sred[1][k] + sred[2][k] + sred[3][k]);
    }
}

// final fp64 reduction of nb rows + scalar finalize, run by one block
__device__ __forceinline__ void finalize_from_partials(
    const double* __restrict__ partial, float* __restrict__ out, int nb)
{
    double loc[9];
    #pragma unroll
    for (int k = 0; k < 9; ++k) loc[k] = 0.0;
    for (int i = threadIdx.x; i < nb; i += BLK1) {
        const double* row = partial + (size_t)i * 9;
        #pragma unroll
        for (int k = 0; k < 9; ++k) loc[k] += row[k];
    }
    #pragma unroll
    for (int k = 0; k < 9; ++k) {
        double v = loc[k];
        #pragma unroll
        for (int off = 32; off > 0; off >>= 1) v += __shfl_down(v, off);
        loc[k] = v;
    }
    __shared__ double dred[BLK1/64][9];
    const int wave = threadIdx.x >> 6;
    const int lane = threadIdx.x & 63;
    if (lane == 0) {
        #pragma unroll
        for (int k = 0; k < 9; ++k) dred[wave][k] = loc[k];
    }
    __syncthreads();
    if (threadIdx.x == 0) {
        const double hws[3] = {4096.0, 1024.0, 256.0};
        double total = 0.0;
        #pragma unroll
        for (int s = 0; s < 3; ++s) {
            double hw = hws[s];
            double tb = dred[0][3*s+0] + dred[1][3*s+0] + dred[2][3*s+0] + dred[3][3*s+0];
            double to = dred[0][3*s+1] + dred[1][3*s+1] + dred[2][3*s+1] + dred[3][3*s+1];
            double tc = dred[0][3*s+2] + dred[1][3*s+2] + dred[2][3*s+2] + dred[3][3*s+2];
            total += 5.0 * (tb / (32.0 * 4.0 * hw))
                   +       (to / (32.0 * hw))
                   +       (tc / (32.0 * 80.0 * hw));
        }
        total /= 3.0;
        total = fmin(fmax(total, 0.0), 1000000.0);
        out[0] = (float)total;
    }
}

// ---------------------------------------------------------------------------
// Cooperative fused kernel: base+corr, grid sync, block 0 finalizes.
// ---------------------------------------------------------------------------
__global__ __launch_bounds__(BLK1, 4) void fused_kernel(
    const float* __restrict__ p0, const float* __restrict__ p1,
    const float* __restrict__ p2,
    const float* __restrict__ boxes, const int* __restrict__ labels,
    double* __restrict__ partial, float* __restrict__ out)
{
    compute_block_partials(p0, p1, p2, boxes, labels, blockIdx.x, GRID1, partial);
    __threadfence();                 // release partials to device scope
    cg::this_grid().sync();          // grid-wide barrier (agent-scope fences)
    if (blockIdx.x == 0) {
        finalize_from_partials(partial, out, GRID1);
    }
}

// ---- fallback path: the proven 2-kernel structure ----
__global__ __launch_bounds__(BLK1) void base_kernel(
    const float* __restrict__ p0, const float* __restrict__ p1,
    const float* __restrict__ p2,
    const float* __restrict__ boxes, const int* __restrict__ labels,
    double* __restrict__ partial)
{
    compute_block_partials(p0, p1, p2, boxes, labels, blockIdx.x, GRID1, partial);
}

__global__ __launch_bounds__(BLK1) void final_kernel(
    const double* __restrict__ partial, float* __restrict__ out)
{
    finalize_from_partials(partial, out, GRID1);
}

extern "C" void kernel_launch(void* const* d_in, const int* in_sizes, int n_in,
                              void* d_out, int out_size, void* d_ws, size_t ws_size,
                              hipStream_t stream)
{
    const float* p0     = (const float*)d_in[0];
    const float* p1     = (const float*)d_in[1];
    const float* p2     = (const float*)d_in[2];
    const float* boxes  = (const float*)d_in[3];
    const int*   labels = (const int*)d_in[4];
    float* out = (float*)d_out;

    double* partial = (double*)d_ws;   // GRID1 * 9 doubles

    void* args[] = { (void*)&p0, (void*)&p1, (void*)&p2,
                     (void*)&boxes, (void*)&labels,
                     (void*)&partial, (void*)&out };
    hipError_t err = hipLaunchCooperativeKernel(
        (const void*)fused_kernel, dim3(GRID1), dim3(BLK1), args, 0, stream);
    if (err != hipSuccess) {
        // fallback: classic 2-kernel reduction
        base_kernel<<<GRID1, BLK1, 0, stream>>>(p0, p1, p2, boxes, labels, partial);
        final_kernel<<<1, BLK1, 0, stream>>>(partial, out);
    }
}

// Round 4
// 194.885 us; speedup vs baseline: 1.2964x; 1.2964x over previous
//
#include <hip/hip_runtime.h>
#include <math.h>

#define NCLS 80
#define BB   32
#define NBOX 50
#define CC   85   // 5 + NUM_CLASSES

#define GRID1 2048
#define BLK1  256

__device__ __forceinline__ float clip10(float x) {
    return fminf(fmaxf(x, -10.f), 10.f);
}

// BCE with target 0: max(x,0) + log1p(exp(-|x|))
__device__ __forceinline__ float bce0(float x) {
    return fmaxf(x, 0.f) + __logf(1.f + __expf(-fabsf(x)));
}

// ---------------------------------------------------------------------------
// Single fused kernel, last-block-done finalize (NO grid.sync — R3 showed
// cg::grid().sync() costs ~140us on 8-XCD MI355X).
//
// Per scale s, per-block partials (fp64):
//   part[3s+0] = sum ch 0..3  clip(x)^2   (+ box corr: (pb-v)^2 - pb^2, last-write-wins)
//   part[3s+1] = sum ch 4     BCE(clip,0) (+ obj corr: -x per target cell, set-union)
//   part[3s+2] = sum ch 5..84 BCE(clip,0) (+ cls corr: -x per (cell,label), set-union)
// Block writes partials, __threadfence (release), atomicAdd ticket (agent
// scope). Last block acquires, reduces all rows, finalizes scalar.
// ---------------------------------------------------------------------------
__global__ __launch_bounds__(BLK1) void fused_kernel(
    const float* __restrict__ p0, const float* __restrict__ p1,
    const float* __restrict__ p2,
    const float* __restrict__ boxes, const int* __restrict__ labels,
    double* __restrict__ partial, unsigned int* __restrict__ ticket,
    float* __restrict__ out)
{
    const int bid = blockIdx.x;
    const int tid = bid * BLK1 + threadIdx.x;
    const int nth = GRID1 * BLK1;
    const float* ps[3] = {p0, p1, p2};
    const int hw4s[3]  = {64*64/4, 32*32/4, 16*16/4};

    float part[9];
    #pragma unroll
    for (int s = 0; s < 3; ++s) {
        const float4* p = (const float4*)ps[s];
        const int hw4 = hw4s[s];                 // pow2: div = shift
        const int n4  = BB * CC * hw4;
        float bx = 0.f, ob = 0.f, cl = 0.f;
        for (int i = tid; i < n4; i += nth) {
            float4 v = p[i];
            int c = (i / hw4) % CC;              // channel (wave-uniform)
            float a0 = clip10(v.x), a1 = clip10(v.y);
            float a2 = clip10(v.z), a3 = clip10(v.w);
            if (c < 4) {
                bx += a0*a0 + a1*a1 + a2*a2 + a3*a3;
            } else if (c == 4) {
                ob += bce0(a0) + bce0(a1) + bce0(a2) + bce0(a3);
            } else {
                cl += bce0(a0) + bce0(a1) + bce0(a2) + bce0(a3);
            }
        }
        part[3*s+0] = bx; part[3*s+1] = ob; part[3*s+2] = cl;
    }

    // ---- sparse corrections (blocks 0..95, wave 0) ----
    __shared__ int   s_cell[NBOX];
    __shared__ int   s_lab[NBOX];
    __shared__ float s_vx[NBOX], s_vy[NBOX], s_vw[NBOX], s_vh[NBOX];

    const bool doCorr = (bid < 3 * BB);
    const int  cs = bid / BB;                    // scale
    const int  cb = bid % BB;                    // image
    const int  Ws[3] = {64, 32, 16};

    if (doCorr && threadIdx.x < 64) {
        const int n = threadIdx.x;
        const int W = Ws[cs];
        if (n < NBOX) {
            const float* bp = boxes + ((size_t)cb * NBOX + n) * 4;
            float gx = bp[0] * (float)W;
            float gy = bp[1] * (float)W;
            int gi = min((int)gx, W - 1);   // gx > 0 always
            int gj = min((int)gy, W - 1);
            s_cell[n] = gj * W + gi;
            s_lab[n]  = labels[cb * NBOX + n];
            s_vx[n] = gx - (float)gi;
            s_vy[n] = gy - (float)gj;
            s_vw[n] = bp[2];
            s_vh[n] = bp[3];
        }
    }
    __syncthreads();
    if (doCorr && threadIdx.x < 64) {
        const int n = threadIdx.x;
        const int W = Ws[cs], hw = W * W;
        const float* pred = ps[cs];
        float cbx = 0.f, cob = 0.f, ccl = 0.f;
        if (n < NBOX) {
            const int cell = s_cell[n], lab = s_lab[n];
            bool lastCell = true, lastCls = true;
            for (int m = n + 1; m < NBOX; ++m) {
                if (s_cell[m] == cell) {
                    lastCell = false;
                    if (s_lab[m] == lab) lastCls = false;
                }
            }
            const float* pb_base = pred + (size_t)(cb * CC) * hw + cell;
            if (lastCell) {
                float vals[4] = {s_vx[n], s_vy[n], s_vw[n], s_vh[n]};
                #pragma unroll
                for (int c = 0; c < 4; ++c) {
                    float pb = clip10(pb_base[c * hw]);
                    float d  = pb - vals[c];
                    cbx += d * d - pb * pb;
                }
                float po = clip10(pb_base[4 * hw]);
                cob -= po;                       // BCE(x,1) - BCE(x,0) = -x
            }
            if (lastCls) {
                float pc = clip10(pb_base[(5 + lab) * hw]);
                ccl -= pc;
            }
        }
        #pragma unroll
        for (int off = 32; off > 0; off >>= 1) {
            cbx += __shfl_down(cbx, off);
            cob += __shfl_down(cob, off);
            ccl += __shfl_down(ccl, off);
        }
        if (n == 0) {
            part[3*cs+0] += cbx;
            part[3*cs+1] += cob;
            part[3*cs+2] += ccl;
        }
    }

    // ---- wave64 shuffle reduce each of the 9 sums ----
    #pragma unroll
    for (int k = 0; k < 9; ++k) {
        float v = part[k];
        #pragma unroll
        for (int off = 32; off > 0; off >>= 1) v += __shfl_down(v, off);
        part[k] = v;
    }
    __shared__ float sred[BLK1/64][9];
    const int wave = threadIdx.x >> 6;
    const int lane = threadIdx.x & 63;
    if (lane == 0) {
        #pragma unroll
        for (int k = 0; k < 9; ++k) sred[wave][k] = part[k];
    }
    __syncthreads();

    // ---- publish partials, grab ticket; last block finalizes ----
    __shared__ bool amLast;
    if (threadIdx.x == 0) {
        double* o = partial + (size_t)bid * 9;
        #pragma unroll
        for (int k = 0; k < 9; ++k)
            o[k] = (double)(sred[0][k] + sred[1][k] + sred[2][k] + sred[3][k]);
        __threadfence();   // release partials to device scope
        unsigned int old = __hip_atomic_fetch_add(
            ticket, 1u, __ATOMIC_ACQ_REL, __HIP_MEMORY_SCOPE_AGENT);
        amLast = (old == GRID1 - 1);
    }
    __syncthreads();
    if (!amLast) return;
    __threadfence();       // acquire: make all blocks' partials visible

    double loc[9];
    #pragma unroll
    for (int k = 0; k < 9; ++k) loc[k] = 0.0;
    for (int i = threadIdx.x; i < GRID1; i += BLK1) {
        const double* row = partial + (size_t)i * 9;
        #pragma unroll
        for (int k = 0; k < 9; ++k) loc[k] += row[k];
    }
    #pragma unroll
    for (int k = 0; k < 9; ++k) {
        double v = loc[k];
        #pragma unroll
        for (int off = 32; off > 0; off >>= 1) v += __shfl_down(v, off);
        loc[k] = v;
    }
    __shared__ double dred[BLK1/64][9];
    if (lane == 0) {
        #pragma unroll
        for (int k = 0; k < 9; ++k) dred[wave][k] = loc[k];
    }
    __syncthreads();
    if (threadIdx.x == 0) {
        const double hws[3] = {4096.0, 1024.0, 256.0};
        double total = 0.0;
        #pragma unroll
        for (int s = 0; s < 3; ++s) {
            double hw = hws[s];
            double tb = dred[0][3*s+0] + dred[1][3*s+0] + dred[2][3*s+0] + dred[3][3*s+0];
            double to = dred[0][3*s+1] + dred[1][3*s+1] + dred[2][3*s+1] + dred[3][3*s+1];
            double tc = dred[0][3*s+2] + dred[1][3*s+2] + dred[2][3*s+2] + dred[3][3*s+2];
            total += 5.0 * (tb / (32.0 * 4.0 * hw))
                   +       (to / (32.0 * hw))
                   +       (tc / (32.0 * 80.0 * hw));
        }
        total /= 3.0;
        total = fmin(fmax(total, 0.0), 1000000.0);
        out[0] = (float)total;
    }
}

extern "C" void kernel_launch(void* const* d_in, const int* in_sizes, int n_in,
                              void* d_out, int out_size, void* d_ws, size_t ws_size,
                              hipStream_t stream)
{
    const float* p0     = (const float*)d_in[0];
    const float* p1     = (const float*)d_in[1];
    const float* p2     = (const float*)d_in[2];
    const float* boxes  = (const float*)d_in[3];
    const int*   labels = (const int*)d_in[4];
    float* out = (float*)d_out;

    double*       partial = (double*)d_ws;                 // GRID1 * 9 doubles
    unsigned int* ticket  = (unsigned int*)((char*)d_ws + GRID1 * 9 * sizeof(double));

    hipMemsetAsync(ticket, 0, sizeof(unsigned int), stream);
    fused_kernel<<<GRID1, BLK1, 0, stream>>>(p0, p1, p2, boxes, labels,
                                             partial, ticket, out);
}

// Round 5
// 103.992 us; speedup vs baseline: 2.4295x; 1.8740x over previous
//
#include <hip/hip_runtime.h>
#include <math.h>

#define NCLS 80
#define BB   32
#define NBOX 50
#define CC   85   // 5 + NUM_CLASSES

#define GRID1 1024   // 4 blocks/CU: saturates HBM, halves partial rows vs 2048
#define BLK1  256

__device__ __forceinline__ float clip10(float x) {
    return fminf(fmaxf(x, -10.f), 10.f);
}

// BCE with target 0: max(x,0) + log1p(exp(-|x|))
__device__ __forceinline__ float bce0(float x) {
    return fmaxf(x, 0.f) + __logf(1.f + __expf(-fabsf(x)));
}

// ---------------------------------------------------------------------------
// K1: dense base sums + sparse target corrections (two-kernel structure on
// purpose: R3/R4 showed any per-block device-scope fence/atomic release
// inside the streaming kernel triggers L2 wb/inv storms that 5x the kernel.
// The kernel boundary is the cheap coherence point.)
//
// Per scale s, per-block partials (fp64, no atomics):
//   part[3s+0] = sum ch 0..3  clip(x)^2   (+ box corr: (pb-v)^2 - pb^2, last-write-wins)
//   part[3s+1] = sum ch 4     BCE(clip,0) (+ obj corr: -x per target cell, set-union)
//   part[3s+2] = sum ch 5..84 BCE(clip,0) (+ cls corr: -x per (cell,label), set-union)
// ---------------------------------------------------------------------------
__global__ __launch_bounds__(BLK1) void base_kernel(
    const float* __restrict__ p0, const float* __restrict__ p1,
    const float* __restrict__ p2,
    const float* __restrict__ boxes, const int* __restrict__ labels,
    double* __restrict__ partial)
{
    const int bid = blockIdx.x;
    const int tid = bid * BLK1 + threadIdx.x;
    const int nth = GRID1 * BLK1;
    const float* ps[3] = {p0, p1, p2};
    const int hw4s[3]  = {64*64/4, 32*32/4, 16*16/4};

    float part[9];
    #pragma unroll
    for (int s = 0; s < 3; ++s) {
        const float4* p = (const float4*)ps[s];
        const int hw4 = hw4s[s];                 // pow2: div = shift
        const int n4  = BB * CC * hw4;
        float bx = 0.f, ob = 0.f, cl = 0.f;
        for (int i = tid; i < n4; i += nth) {
            float4 v = p[i];
            int c = (i / hw4) % CC;              // channel (wave-uniform)
            float a0 = clip10(v.x), a1 = clip10(v.y);
            float a2 = clip10(v.z), a3 = clip10(v.w);
            if (c < 4) {
                bx += a0*a0 + a1*a1 + a2*a2 + a3*a3;
            } else if (c == 4) {
                ob += bce0(a0) + bce0(a1) + bce0(a2) + bce0(a3);
            } else {
                cl += bce0(a0) + bce0(a1) + bce0(a2) + bce0(a3);
            }
        }
        part[3*s+0] = bx; part[3*s+1] = ob; part[3*s+2] = cl;
    }

    // ---- sparse corrections (blocks 0..95, wave 0) ----
    __shared__ int   s_cell[NBOX];
    __shared__ int   s_lab[NBOX];
    __shared__ float s_vx[NBOX], s_vy[NBOX], s_vw[NBOX], s_vh[NBOX];

    const bool doCorr = (bid < 3 * BB);
    const int  cs = bid / BB;                    // scale
    const int  cb = bid % BB;                    // image
    const int  Ws[3] = {64, 32, 16};

    if (doCorr && threadIdx.x < 64) {
        const int n = threadIdx.x;
        const int W = Ws[cs];
        if (n < NBOX) {
            const float* bp = boxes + ((size_t)cb * NBOX + n) * 4;
            float gx = bp[0] * (float)W;
            float gy = bp[1] * (float)W;
            int gi = min((int)gx, W - 1);   // gx > 0 always
            int gj = min((int)gy, W - 1);
            s_cell[n] = gj * W + gi;
            s_lab[n]  = labels[cb * NBOX + n];
            s_vx[n] = gx - (float)gi;
            s_vy[n] = gy - (float)gj;
            s_vw[n] = bp[2];
            s_vh[n] = bp[3];
        }
    }
    __syncthreads();
    if (doCorr && threadIdx.x < 64) {
        const int n = threadIdx.x;
        const int W = Ws[cs], hw = W * W;
        const float* pred = ps[cs];
        float cbx = 0.f, cob = 0.f, ccl = 0.f;
        if (n < NBOX) {
            const int cell = s_cell[n], lab = s_lab[n];
            bool lastCell = true, lastCls = true;
            for (int m = n + 1; m < NBOX; ++m) {
                if (s_cell[m] == cell) {
                    lastCell = false;
                    if (s_lab[m] == lab) lastCls = false;
                }
            }
            const float* pb_base = pred + (size_t)(cb * CC) * hw + cell;
            if (lastCell) {
                float vals[4] = {s_vx[n], s_vy[n], s_vw[n], s_vh[n]};
                #pragma unroll
                for (int c = 0; c < 4; ++c) {
                    float pb = clip10(pb_base[c * hw]);
                    float d  = pb - vals[c];
                    cbx += d * d - pb * pb;
                }
                float po = clip10(pb_base[4 * hw]);
                cob -= po;                       // BCE(x,1) - BCE(x,0) = -x
            }
            if (lastCls) {
                float pc = clip10(pb_base[(5 + lab) * hw]);
                ccl -= pc;
            }
        }
        #pragma unroll
        for (int off = 32; off > 0; off >>= 1) {
            cbx += __shfl_down(cbx, off);
            cob += __shfl_down(cob, off);
            ccl += __shfl_down(ccl, off);
        }
        if (n == 0) {
            part[3*cs+0] += cbx;
            part[3*cs+1] += cob;
            part[3*cs+2] += ccl;
        }
    }

    // ---- wave64 shuffle reduce each of the 9 sums ----
    #pragma unroll
    for (int k = 0; k < 9; ++k) {
        float v = part[k];
        #pragma unroll
        for (int off = 32; off > 0; off >>= 1) v += __shfl_down(v, off);
        part[k] = v;
    }
    __shared__ float sred[BLK1/64][9];
    const int wave = threadIdx.x >> 6;
    const int lane = threadIdx.x & 63;
    if (lane == 0) {
        #pragma unroll
        for (int k = 0; k < 9; ++k) sred[wave][k] = part[k];
    }
    __syncthreads();
    if (threadIdx.x == 0) {
        double* o = partial + (size_t)bid * 9;
        #pragma unroll
        for (int k = 0; k < 9; ++k)
            o[k] = (double)(sred[0][k] + sred[1][k] + sred[2][k] + sred[3][k]);
    }
}

// ---------------------------------------------------------------------------
// K2: reduce per-block fp64 partials via wave shuffles, finalize scalar.
// ---------------------------------------------------------------------------
__global__ __launch_bounds__(BLK1) void final_kernel(
    const double* __restrict__ partial, float* __restrict__ out)
{
    double loc[9];
    #pragma unroll
    for (int k = 0; k < 9; ++k) loc[k] = 0.0;
    for (int i = threadIdx.x; i < GRID1; i += BLK1) {
        const double* row = partial + (size_t)i * 9;
        #pragma unroll
        for (int k = 0; k < 9; ++k) loc[k] += row[k];
    }
    #pragma unroll
    for (int k = 0; k < 9; ++k) {
        double v = loc[k];
        #pragma unroll
        for (int off = 32; off > 0; off >>= 1) v += __shfl_down(v, off);
        loc[k] = v;
    }
    __shared__ double dred[BLK1/64][9];
    const int wave = threadIdx.x >> 6;
    const int lane = threadIdx.x & 63;
    if (lane == 0) {
        #pragma unroll
        for (int k = 0; k < 9; ++k) dred[wave][k] = loc[k];
    }
    __syncthreads();
    if (threadIdx.x == 0) {
        const double hws[3] = {4096.0, 1024.0, 256.0};
        double total = 0.0;
        #pragma unroll
        for (int s = 0; s < 3; ++s) {
            double hw = hws[s];
            double tb = dred[0][3*s+0] + dred[1][3*s+0] + dred[2][3*s+0] + dred[3][3*s+0];
            double to = dred[0][3*s+1] + dred[1][3*s+1] + dred[2][3*s+1] + dred[3][3*s+1];
            double tc = dred[0][3*s+2] + dred[1][3*s+2] + dred[2][3*s+2] + dred[3][3*s+2];
            total += 5.0 * (tb / (32.0 * 4.0 * hw))
                   +       (to / (32.0 * hw))
                   +       (tc / (32.0 * 80.0 * hw));
        }
        total /= 3.0;
        total = fmin(fmax(total, 0.0), 1000000.0);
        out[0] = (float)total;
    }
}

extern "C" void kernel_launch(void* const* d_in, const int* in_sizes, int n_in,
                              void* d_out, int out_size, void* d_ws, size_t ws_size,
                              hipStream_t stream)
{
    const float* p0     = (const float*)d_in[0];
    const float* p1     = (const float*)d_in[1];
    const float* p2     = (const float*)d_in[2];
    const float* boxes  = (const float*)d_in[3];
    const int*   labels = (const int*)d_in[4];
    float* out = (float*)d_out;

    double* partial = (double*)d_ws;   // GRID1 * 9 doubles

    base_kernel<<<GRID1, BLK1, 0, stream>>>(p0, p1, p2, boxes, labels, partial);
    final_kernel<<<1, BLK1, 0, stream>>>(partial, out);
}